// Round 1
// baseline (74.493 us; speedup 1.0000x reference)
//
#include <hip/hip_runtime.h>

#define NQ 12
#define DIM 4096
#define NLAYERS 2
#define PSIZE 24   // NQ * NLAYERS

// One wave (64 lanes) per batch item. State (4096 f32) lives in LDS.
__global__ __launch_bounds__(64)
void qsim_kernel(const float* __restrict__ xin,
                 const float* __restrict__ W1,
                 const float* __restrict__ b1,
                 const float* __restrict__ W2,
                 const float* __restrict__ b2,
                 float* __restrict__ out)
{
    __shared__ float st[DIM];
    __shared__ float cs[PSIZE];
    __shared__ float sn[PSIZE];

    const int b    = blockIdx.x;
    const int lane = threadIdx.x;

    // ---- fused MLP: params[m] = b2[m] + sum_k relu(x*W1[k]+b1[k]) * W2[m,k]
    if (lane < PSIZE) {
        const float xb = xin[b];
        float acc = b2[lane];
        #pragma unroll
        for (int k = 0; k < 32; ++k) {
            float h = fmaf(xb, W1[k], b1[k]);
            h = fmaxf(h, 0.0f);
            acc = fmaf(h, W2[lane * 32 + k], acc);
        }
        const float half = 0.5f * acc;
        cs[lane] = cosf(half);
        sn[lane] = sinf(half);
    }

    // ---- init |0...0>
    #pragma unroll
    for (int k = 0; k < 64; ++k)
        st[lane + 64 * k] = 0.0f;
    if (lane == 0) st[0] = 1.0f;
    __syncthreads();

    for (int l = 0; l < NLAYERS; ++l) {
        // ---- RY rotations, qubit j pairs indices at stride S = 2^(11-j)
        #pragma unroll 1
        for (int j = 0; j < NQ; ++j) {
            const float c = cs[l * NQ + j];
            const float s = sn[l * NQ + j];
            const int S = 1 << (11 - j);
            #pragma unroll
            for (int k = 0; k < 32; ++k) {
                const int p  = lane + 64 * k;              // pair id in [0,2048)
                const int i0 = ((p & ~(S - 1)) << 1) | (p & (S - 1));
                const int i1 = i0 + S;
                const float a0 = st[i0];
                const float a1 = st[i1];
                st[i0] = c * a0 - s * a1;
                st[i1] = s * a0 + c * a1;
            }
            __syncthreads();
        }
        // ---- CNOT(j -> j+1): control bit 11-j, target bit 10-j
        #pragma unroll 1
        for (int j = 0; j < NQ - 1; ++j) {
            const int tb = 10 - j;
            const int T  = 1 << tb;
            #pragma unroll
            for (int k = 0; k < 16; ++k) {
                const int q  = lane + 64 * k;              // swap id in [0,1024)
                const int lo = q & (T - 1);
                const int hi = q >> tb;
                const int i0 = (hi << (tb + 2)) | (T << 1) | lo; // ctrl=1, tgt=0
                const int i1 = i0 | T;                           // ctrl=1, tgt=1
                const float a  = st[i0];
                const float bb = st[i1];
                st[i0] = bb;
                st[i1] = a;
            }
            __syncthreads();
        }
    }

    // ---- <Z_0>: sign = +1 for index bit 11 == 0, else -1
    float acc = 0.0f;
    #pragma unroll
    for (int k = 0; k < 64; ++k) {
        const float v = st[lane + 64 * k];   // bit 11 of index == (k & 32)
        acc = (k & 32) ? fmaf(-v, v, acc) : fmaf(v, v, acc);
    }
    #pragma unroll
    for (int off = 32; off >= 1; off >>= 1)
        acc += __shfl_xor(acc, off);
    if (lane == 0) out[b] = acc;
}

extern "C" void kernel_launch(void* const* d_in, const int* in_sizes, int n_in,
                              void* d_out, int out_size, void* d_ws, size_t ws_size,
                              hipStream_t stream)
{
    const float* xin = (const float*)d_in[0];
    const float* W1  = (const float*)d_in[1];
    const float* b1  = (const float*)d_in[2];
    const float* W2  = (const float*)d_in[3];
    const float* b2  = (const float*)d_in[4];
    float* out = (float*)d_out;

    qsim_kernel<<<2048, 64, 0, stream>>>(xin, W1, b1, W2, b2, out);
}

// Round 2
// 42.192 us; speedup vs baseline: 1.7656x; 1.7656x over previous
//
#include <hip/hip_runtime.h>

#define NQ 12
#define DIM 4096
#define NLAYERS 2
#define PSIZE 24   // NQ * NLAYERS

// One wave (64 lanes) per batch item. State (4096 f32) fully register-resident:
// lane holds amplitude of index i = (r << 6) | lane for r = 0..63.
//   index bits 0-5  = lane bits  -> gates via __shfl_xor (conflict-free)
//   index bits 6-11 = register bits -> gates via pure register FMA / renames
__global__ __launch_bounds__(64)
void qsim_reg(const float* __restrict__ xin,
              const float* __restrict__ W1,
              const float* __restrict__ b1,
              const float* __restrict__ W2,
              const float* __restrict__ b2,
              float* __restrict__ out)
{
    __shared__ float cs[PSIZE];
    __shared__ float sn[PSIZE];

    const int b    = blockIdx.x;
    const int lane = threadIdx.x;

    // ---- fused MLP: params[m] = b2[m] + sum_k relu(x*W1[k]+b1[k]) * W2[m,k]
    if (lane < PSIZE) {
        const float xb = xin[b];
        float acc = b2[lane];
        #pragma unroll
        for (int k = 0; k < 32; ++k) {
            float h = fmaf(xb, W1[k], b1[k]);
            h = fmaxf(h, 0.0f);
            acc = fmaf(h, W2[lane * 32 + k], acc);
        }
        const float half = 0.5f * acc;
        cs[lane] = cosf(half);
        sn[lane] = sinf(half);
    }

    // ---- init |0...0>
    float v[64];
    #pragma unroll
    for (int r = 1; r < 64; ++r) v[r] = 0.0f;
    v[0] = (lane == 0) ? 1.0f : 0.0f;

    __syncthreads();

    #pragma unroll 1
    for (int l = 0; l < NLAYERS; ++l) {
        const int pb = l * NQ;

        // ---- RY rotations j=0..5: stride S=2^(11-j) >= 64 -> register bit (5-j)
        #pragma unroll
        for (int j = 0; j < 6; ++j) {
            const float c = cs[pb + j];
            const float s = sn[pb + j];
            const int m = 1 << (5 - j);
            #pragma unroll
            for (int r = 0; r < 64; ++r) {
                if (!(r & m)) {
                    const float a0 = v[r];
                    const float a1 = v[r | m];
                    v[r]     = fmaf(c, a0, -s * a1);
                    v[r | m] = fmaf(s, a0,  c * a1);
                }
            }
        }

        // ---- RY rotations j=6..11: stride S=2^(11-j) < 64 -> lane bit
        #pragma unroll
        for (int j = 6; j < 12; ++j) {
            const float c = cs[pb + j];
            const float s = sn[pb + j];
            const int S = 1 << (11 - j);
            const float sgn = (lane & S) ? s : -s;
            #pragma unroll
            for (int r = 0; r < 64; ++r) {
                const float p = __shfl_xor(v[r], S, 64);
                v[r] = fmaf(sgn, p, c * v[r]);
            }
        }

        // ---- CNOT j=0..4: control bit 11-j (reg bit 5-j), target bit 10-j (reg bit 4-j)
        //      pure register permutation (free after SSA renaming)
        #pragma unroll
        for (int j = 0; j < 5; ++j) {
            const int cM = 1 << (5 - j);
            const int tM = 1 << (4 - j);
            #pragma unroll
            for (int r = 0; r < 64; ++r) {
                if ((r & cM) && !(r & tM)) {
                    const float t = v[r];
                    v[r] = v[r | tM];
                    v[r | tM] = t;
                }
            }
        }

        // ---- CNOT j=5: control bit 6 (reg bit 0), target bit 5 (lane bit 5)
        #pragma unroll
        for (int r = 1; r < 64; r += 2)
            v[r] = __shfl_xor(v[r], 32, 64);

        // ---- CNOT j=6..10: control bit 11-j (lane), target bit 10-j (lane)
        #pragma unroll
        for (int j = 6; j < 11; ++j) {
            const int C = 1 << (11 - j);
            const int T = 1 << (10 - j);
            const bool ctl = (lane & C) != 0;
            #pragma unroll
            for (int r = 0; r < 64; ++r) {
                const float p = __shfl_xor(v[r], T, 64);
                v[r] = ctl ? p : v[r];
            }
        }
    }

    // ---- <Z_0>: sign from index bit 11 = register bit 5
    float acc = 0.0f;
    #pragma unroll
    for (int r = 0; r < 64; ++r) {
        const float t = (r & 32) ? -v[r] : v[r];
        acc = fmaf(v[r], t, acc);
    }
    #pragma unroll
    for (int off = 32; off >= 1; off >>= 1)
        acc += __shfl_xor(acc, off, 64);
    if (lane == 0) out[b] = acc;
}

extern "C" void kernel_launch(void* const* d_in, const int* in_sizes, int n_in,
                              void* d_out, int out_size, void* d_ws, size_t ws_size,
                              hipStream_t stream)
{
    const float* xin = (const float*)d_in[0];
    const float* W1  = (const float*)d_in[1];
    const float* b1  = (const float*)d_in[2];
    const float* W2  = (const float*)d_in[3];
    const float* b2  = (const float*)d_in[4];
    float* out = (float*)d_out;

    qsim_reg<<<2048, 64, 0, stream>>>(xin, W1, b1, W2, b2, out);
}

// Round 4
// 33.531 us; speedup vs baseline: 2.2217x; 1.2583x over previous
//
#include <hip/hip_runtime.h>

#define PSIZE 24

// One wave per batch item; state register-resident: lane holds amplitude of
// physical index p = (r << 6) | lane for r = 0..63.
//   p bits 0-5  = lane bits   -> cross-lane gates via __shfl_xor
//   p bits 6-11 = register bits -> pure register gates (compile-time masks)
//
// CNOT chains are folded into a GF(2) index map (never executed):
//   chain map L: bit k of L(x) = parity(x bits k..11)   (bit 11 invariant)
//   after skipping layer-1 chain, stored slot p holds true index L(p).
//   layer-2 RY on true bit t: stored pair mask = L^-1(e_t) = e_t|e_{t-1}
//   (e_0 alone for t=0); role (s0 vs s1) = parity(p & bits[t..11]).
//   After layer-2 chain, measurement bit = bit11(L(L(p))) = bit11(p) = reg bit 5.
__global__ __launch_bounds__(64)
void qsim_fold(const float* __restrict__ xin,
               const float* __restrict__ W1,
               const float* __restrict__ b1,
               const float* __restrict__ W2,
               const float* __restrict__ b2,
               float* __restrict__ out)
{
    __shared__ float cs[PSIZE], sn[PSIZE];
    const int b    = blockIdx.x;
    const int lane = threadIdx.x;

    // fused MLP: params[m] = b2[m] + sum_k relu(x*W1[k]+b1[k]) * W2[m,k]
    if (lane < PSIZE) {
        const float xb = xin[b];
        float acc = b2[lane];
        #pragma unroll
        for (int k = 0; k < 32; ++k) {
            float h = fmaf(xb, W1[k], b1[k]);
            h = fmaxf(h, 0.0f);
            acc = fmaf(h, W2[lane * 32 + k], acc);
        }
        const float half = 0.5f * acc;
        cs[lane] = cosf(half);
        sn[lane] = sinf(half);
    }

    float v[64];
    #pragma unroll
    for (int r = 1; r < 64; ++r) v[r] = 0.0f;
    v[0] = (lane == 0) ? 1.0f : 0.0f;
    __syncthreads();

    // =================== LAYER 1 (storage = true indices) ===================
    // reg-bit rotations j=0..5 (physical bits 11..6)
    #pragma unroll
    for (int j = 0; j < 6; ++j) {
        const float c = cs[j], s = sn[j];
        const int m = 1 << (5 - j);
        #pragma unroll
        for (int r = 0; r < 64; ++r) if (!(r & m)) {
            const float a0 = v[r], a1 = v[r | m];
            v[r]     = fmaf(c, a0, -s * a1);
            v[r | m] = fmaf(s, a0,  c * a1);
        }
    }
    // lane-bit rotations j=6..11 (physical bits 5..0), S = 32,16,8,4,2,1
    #pragma unroll
    for (int j = 6; j < 12; ++j) {
        const float c = cs[j], s = sn[j];
        const int S = 1 << (11 - j);
        const float sgn = (lane & S) ? s : -s;
        #pragma unroll
        for (int r = 0; r < 64; ++r) {
            const float p = __shfl_xor(v[r], S, 64);
            v[r] = fmaf(sgn, p, c * v[r]);
        }
    }
    // layer-1 CNOT chain: folded into index map (no data movement)

    // =================== LAYER 2 (stored p holds true index L(p)) ===========
    // t = 11..7 (qubits 0..4, cs[12..16]): pair mask in reg bits, role from reg parity
    #pragma unroll
    for (int g = 0; g < 5; ++g) {                     // t = 11 - g
        const float c = cs[12 + g], s = sn[12 + g];
        const int rm  = 0x30 >> g;                    // reg bits of e_t|e_{t-1}
        const int suf = (0x3F << (5 - g)) & 0x3F;     // reg bits of [t..11]
        #pragma unroll
        for (int r = 0; r < 64; ++r) {
            if ((__builtin_popcount(r & suf) & 1) == 0) {   // s0 role
                const float a0 = v[r], a1 = v[r ^ rm];
                v[r]      = fmaf(c, a0, -s * a1);
                v[r ^ rm] = fmaf(s, a0,  c * a1);
            }
        }
    }
    { // t=6 (qubit 5, cs[17]): pair (r,l) <-> (r^1, l^32); role = popc(r) parity
        const float c = cs[17], s = sn[17];
        #pragma unroll
        for (int r = 0; r < 64; r += 2) {
            const float pe = __shfl_xor(v[r | 1], 32, 64);  // partner of v[r]
            const float po = __shfl_xor(v[r],     32, 64);  // partner of v[r|1]
            if ((__builtin_popcount(r) & 1) == 0) {
                v[r]     = fmaf(c, v[r], -s * pe);          // s0
                v[r | 1] = fmaf(s, po,  c * v[r | 1]);      // s1
            } else {
                v[r]     = fmaf(s, pe,  c * v[r]);          // s1
                v[r | 1] = fmaf(c, v[r | 1], -s * po);      // s0
            }
        }
    }
    // t = 5..2 (qubits 6..9, cs[18..21]): lane masks 48,24,12,6
    #pragma unroll
    for (int g = 0; g < 4; ++g) {                     // t = 5 - g
        const float c = cs[18 + g], s = sn[18 + g];
        const int lm   = 48 >> g;
        const int lsuf = (0x3F << (5 - g)) & 0x3F;    // lane bits of [t..5]
        const float sl = (__popc(lane & lsuf) & 1) ? s : -s;
        #pragma unroll
        for (int r = 0; r < 64; ++r) {
            const float p  = __shfl_xor(v[r], lm, 64);
            const float sg = (__builtin_popcount(r) & 1) ? -sl : sl;
            v[r] = fmaf(sg, p, c * v[r]);
        }
    }
    { // t=1 (qubit 10, cs[22]): lane mask 3
        const float c = cs[22], s = sn[22];
        const float sl = (__popc(lane & 0x3E) & 1) ? s : -s;
        #pragma unroll
        for (int r = 0; r < 64; ++r) {
            const float p  = __shfl_xor(v[r], 3, 64);
            const float sg = (__builtin_popcount(r) & 1) ? -sl : sl;
            v[r] = fmaf(sg, p, c * v[r]);
        }
    }
    { // t=0 (qubit 11, cs[23]): lane mask 1
        const float c = cs[23], s = sn[23];
        const float sl = (__popc(lane & 0x3F) & 1) ? s : -s;
        #pragma unroll
        for (int r = 0; r < 64; ++r) {
            const float p  = __shfl_xor(v[r], 1, 64);
            const float sg = (__builtin_popcount(r) & 1) ? -sl : sl;
            v[r] = fmaf(sg, p, c * v[r]);
        }
    }
    // layer-2 CNOT chain folded: measurement bit = physical bit 11 = reg bit 5

    // <Z_0>
    float acc = 0.0f;
    #pragma unroll
    for (int r = 0; r < 64; ++r) {
        const float t = (r & 32) ? -v[r] : v[r];
        acc = fmaf(v[r], t, acc);
    }
    #pragma unroll
    for (int off = 32; off >= 1; off >>= 1)
        acc += __shfl_xor(acc, off, 64);
    if (lane == 0) out[b] = acc;
}

extern "C" void kernel_launch(void* const* d_in, const int* in_sizes, int n_in,
                              void* d_out, int out_size, void* d_ws, size_t ws_size,
                              hipStream_t stream)
{
    const float* xin = (const float*)d_in[0];
    const float* W1  = (const float*)d_in[1];
    const float* b1  = (const float*)d_in[2];
    const float* W2  = (const float*)d_in[3];
    const float* b2  = (const float*)d_in[4];
    float* out = (float*)d_out;

    qsim_fold<<<2048, 64, 0, stream>>>(xin, W1, b1, W2, b2, out);
}